// Round 1
// baseline (738.004 us; speedup 1.0000x reference)
//
#include <hip/hip_runtime.h>
#include <hip/hip_bf16.h>
#include <math.h>

#define T_SEQ   2048
#define D_MODEL 4096
#define N_Q     32
#define N_KV    8
#define HDIM    128
#define NH      (N_Q * HDIM)      // 4096
#define KH      (N_KV * HDIM)     // 1024
#define QKV_W   (NH + 2 * KH)     // 6144

using bf16   = __hip_bfloat16;
using short8 = __attribute__((ext_vector_type(8))) short;
using floatx4 = __attribute__((ext_vector_type(4))) float;

// ---------------------------------------------------------------- helpers
__device__ __forceinline__ void load_lds16(const bf16* g, bf16* l) {
  __builtin_amdgcn_global_load_lds((const __attribute__((address_space(1))) void*)g,
                                   (__attribute__((address_space(3))) void*)l,
                                   16, 0, 0);
}
__device__ __forceinline__ void store_out(bf16* p, float v) { *p = __float2bfloat16(v); }
__device__ __forceinline__ void store_out(float* p, float v) { *p = v; }

// ---------------------------------------------------------------- x -> bf16
__global__ void cvt_bf16_kernel(const float* __restrict__ src, bf16* __restrict__ dst, int n4) {
  int i = blockIdx.x * 256 + threadIdx.x;
  if (i < n4) {
    const float4 v = ((const float4*)src)[i];
    union { bf16 h[4]; unsigned long long u; } o;
    o.h[0] = __float2bfloat16(v.x); o.h[1] = __float2bfloat16(v.y);
    o.h[2] = __float2bfloat16(v.z); o.h[3] = __float2bfloat16(v.w);
    ((unsigned long long*)dst)[i] = o.u;
  }
}

// ------------------------------------------------- fp32 (R,C) -> bf16 (C,R)
__global__ void transpose_cvt(const float* __restrict__ src, bf16* __restrict__ dst,
                              int R, int C) {
  __shared__ float tile[32][33];
  const int bx = blockIdx.x * 32;          // col base of src
  const int by = blockIdx.y * 32;          // row base of src
  const int tx = threadIdx.x & 31, ty = threadIdx.x >> 5;   // ty 0..7
#pragma unroll
  for (int i = 0; i < 32; i += 8)
    tile[ty + i][tx] = src[(size_t)(by + ty + i) * C + bx + tx];
  __syncthreads();
#pragma unroll
  for (int i = 0; i < 32; i += 8)
    dst[(size_t)(bx + ty + i) * R + by + tx] = __float2bfloat16(tile[tx][ty + i]);
}

// ------------------------------------------------- GEMM C[M,N] = A[M,K] * B[N,K]^T
// m97 structure: 128x128 block tile, BK=32, 4 waves (64x64 each), global_load_lds w16.
template <typename OutT>
__global__ __launch_bounds__(256)
void gemm_bt(const bf16* __restrict__ A, const bf16* __restrict__ B,
             OutT* __restrict__ C, int M, int N, int Kc) {
  __shared__ bf16 As[128 * 32];
  __shared__ bf16 Bs[128 * 32];
  const int tid  = threadIdx.x;
  const int lane = tid & 63;
  const int wave = tid >> 6;
  const int bm = blockIdx.x * 128;
  const int bn = blockIdx.y * 128;
  const int wm = (wave >> 1) * 64;
  const int wn = (wave & 1) * 64;
  const int r = lane & 15, q = lane >> 4;

  floatx4 acc[4][4];
  const floatx4 zero = {0.f, 0.f, 0.f, 0.f};
#pragma unroll
  for (int i = 0; i < 4; i++)
#pragma unroll
    for (int j = 0; j < 4; j++) acc[i][j] = zero;

  // staging: each wave loads 32 rows of A-tile and B-tile (2 insts of 16 rows each)
  const int srow = wave * 32 + (lane >> 2);
  const int scol = (lane & 3) * 8;
  const bf16* gA = A + (size_t)(bm + srow) * Kc + scol;
  const bf16* gB = B + (size_t)(bn + srow) * Kc + scol;
  bf16* lA = As + wave * 32 * 32;
  bf16* lB = Bs + wave * 32 * 32;

  for (int k0 = 0; k0 < Kc; k0 += 32) {
    __syncthreads();
    load_lds16(gA + k0,                lA);
    load_lds16(gA + k0 + 16 * (size_t)Kc, lA + 16 * 32);
    load_lds16(gB + k0,                lB);
    load_lds16(gB + k0 + 16 * (size_t)Kc, lB + 16 * 32);
    __syncthreads();

    short8 af[4], bfr[4];
#pragma unroll
    for (int mt = 0; mt < 4; mt++)
      af[mt] = *(const short8*)(As + (wm + mt * 16 + r) * 32 + q * 8);
#pragma unroll
    for (int nt = 0; nt < 4; nt++)
      bfr[nt] = *(const short8*)(Bs + (wn + nt * 16 + r) * 32 + q * 8);
#pragma unroll
    for (int mt = 0; mt < 4; mt++)
#pragma unroll
      for (int nt = 0; nt < 4; nt++)
        acc[mt][nt] = __builtin_amdgcn_mfma_f32_16x16x32_bf16(af[mt], bfr[nt], acc[mt][nt], 0, 0, 0);
  }

#pragma unroll
  for (int mt = 0; mt < 4; mt++)
#pragma unroll
    for (int nt = 0; nt < 4; nt++)
#pragma unroll
      for (int reg = 0; reg < 4; reg++) {
        const int row = bm + wm + mt * 16 + q * 4 + reg;
        const int col = bn + wn + nt * 16 + r;
        store_out(&C[(size_t)row * N + col], acc[mt][nt][reg]);
      }
}

// ------------------------------------------------- RoPE + split + V transpose
__global__ void rope_kernel(const bf16* __restrict__ QKV, const int* __restrict__ positions,
                            bf16* __restrict__ Q, bf16* __restrict__ Kr, bf16* __restrict__ Vt) {
  const int t = blockIdx.x;
  const float pos = (float)positions[t];
  const bf16* row = QKV + (size_t)t * QKV_W;
  for (int idx = threadIdx.x; idx < N_Q * 64; idx += 256) {
    const int n = idx >> 6, hh = idx & 63;
    const float inv = powf(10000.f, -(float)hh * (1.f / 64.f));
    float sn, cs; sincosf(pos * inv, &sn, &cs);
    const float x1 = __bfloat162float(row[n * HDIM + hh]);
    const float x2 = __bfloat162float(row[n * HDIM + hh + 64]);
    Q[(size_t)t * NH + n * HDIM + hh]      = __float2bfloat16(x1 * cs - x2 * sn);
    Q[(size_t)t * NH + n * HDIM + hh + 64] = __float2bfloat16(x2 * cs + x1 * sn);
  }
  for (int idx = threadIdx.x; idx < N_KV * 64; idx += 256) {
    const int kh = idx >> 6, hh = idx & 63;
    const float inv = powf(10000.f, -(float)hh * (1.f / 64.f));
    float sn, cs; sincosf(pos * inv, &sn, &cs);
    const float x1 = __bfloat162float(row[NH + kh * HDIM + hh]);
    const float x2 = __bfloat162float(row[NH + kh * HDIM + hh + 64]);
    Kr[(size_t)t * KH + kh * HDIM + hh]      = __float2bfloat16(x1 * cs - x2 * sn);
    Kr[(size_t)t * KH + kh * HDIM + hh + 64] = __float2bfloat16(x2 * cs + x1 * sn);
  }
  for (int idx = threadIdx.x; idx < KH; idx += 256) {
    Vt[(size_t)idx * T_SEQ + t] = row[NH + KH + idx];   // Vt[(kh*H+h)][t]
  }
}

// ------------------------------------------------- causal GQA flash attention
// block: 64 q rows (4 waves x 16), iterate 64-kv-col tiles up to the diagonal.
__global__ __launch_bounds__(256)
void flash_attn(const bf16* __restrict__ Q, const bf16* __restrict__ Kk,
                const bf16* __restrict__ Vt, bf16* __restrict__ O) {
  const int n  = blockIdx.y;       // q head
  const int kh = n >> 2;           // kv head (G=4)
  const int bt = blockIdx.x;
  const int t0 = bt * 64;
  const int tid = threadIdx.x, lane = tid & 63, wave = tid >> 6;
  const int r = lane & 15, q = lane >> 4;

  __shared__ bf16 Ks[64][136];     // [s][h], padded (stride 272B)
  __shared__ bf16 Vs[128][72];     // [h][s], padded (stride 144B)
  __shared__ bf16 Ps[4][16][72];   // per-wave P, padded

  // Q fragments live in registers for the whole block
  short8 qf[4];
  {
    const bf16* qrow = Q + (size_t)(t0 + wave * 16 + r) * NH + n * HDIM;
#pragma unroll
    for (int ks = 0; ks < 4; ks++)
      qf[ks] = *(const short8*)(qrow + ks * 32 + q * 8);
  }

  floatx4 o_acc[8];
  const floatx4 zero = {0.f, 0.f, 0.f, 0.f};
#pragma unroll
  for (int i = 0; i < 8; i++) o_acc[i] = zero;
  float m_i[4], l_i[4];
#pragma unroll
  for (int i = 0; i < 4; i++) { m_i[i] = -INFINITY; l_i[i] = 0.f; }

  const float scl = 0.08838834764831845f * 1.44269504088896341f;  // 1/sqrt(H) * log2(e)

  for (int it = 0; it <= bt; ++it) {
    const int s0 = it * 64;
    __syncthreads();
    // stage K tile (64 x 128) and V^T tile (128 x 64)
#pragma unroll
    for (int c = 0; c < 4; c++) {
      const int chunk = tid + 256 * c;
      const int s = chunk >> 4, h8 = (chunk & 15) * 8;
      *(short8*)(&Ks[s][h8]) = *(const short8*)(Kk + (size_t)(s0 + s) * KH + kh * HDIM + h8);
    }
#pragma unroll
    for (int c = 0; c < 4; c++) {
      const int chunk = tid + 256 * c;
      const int h = chunk >> 3, s8 = (chunk & 7) * 8;
      *(short8*)(&Vs[h][s8]) = *(const short8*)(Vt + ((size_t)kh * HDIM + h) * T_SEQ + s0 + s8);
    }
    __syncthreads();

    // S = Q K^T  (wave: 16 rows x 64 cols)
    floatx4 sa[4];
#pragma unroll
    for (int nt = 0; nt < 4; nt++) sa[nt] = zero;
#pragma unroll
    for (int ks = 0; ks < 4; ks++)
#pragma unroll
      for (int nt = 0; nt < 4; nt++) {
        const short8 kb = *(const short8*)(&Ks[nt * 16 + r][ks * 32 + q * 8]);
        sa[nt] = __builtin_amdgcn_mfma_f32_16x16x32_bf16(qf[ks], kb, sa[nt], 0, 0, 0);
      }

    // scale (into log2 units), causal mask, row max
    const bool diag = (it == bt);
    float mloc[4];
#pragma unroll
    for (int reg = 0; reg < 4; reg++) mloc[reg] = -INFINITY;
#pragma unroll
    for (int nt = 0; nt < 4; nt++)
#pragma unroll
      for (int reg = 0; reg < 4; reg++) {
        float s = sa[nt][reg] * scl;
        if (diag) {
          const int trow = wave * 16 + q * 4 + reg;
          const int scol = nt * 16 + r;
          if (scol > trow) s = -INFINITY;
        }
        sa[nt][reg] = s;
        mloc[reg] = fmaxf(mloc[reg], s);
      }
#pragma unroll
    for (int reg = 0; reg < 4; reg++) {
      float v = mloc[reg];
      v = fmaxf(v, __shfl_xor(v, 1));
      v = fmaxf(v, __shfl_xor(v, 2));
      v = fmaxf(v, __shfl_xor(v, 4));
      v = fmaxf(v, __shfl_xor(v, 8));
      mloc[reg] = v;
    }

    float alpha[4], lloc[4];
#pragma unroll
    for (int reg = 0; reg < 4; reg++) {
      const float mnew = fmaxf(m_i[reg], mloc[reg]);
      alpha[reg] = exp2f(m_i[reg] - mnew);
      m_i[reg] = mnew;
      lloc[reg] = 0.f;
    }
    // P = exp2(S - m), write to LDS in A-layout source form
#pragma unroll
    for (int nt = 0; nt < 4; nt++)
#pragma unroll
      for (int reg = 0; reg < 4; reg++) {
        const float p = exp2f(sa[nt][reg] - m_i[reg]);
        lloc[reg] += p;
        Ps[wave][q * 4 + reg][nt * 16 + r] = __float2bfloat16(p);
      }
#pragma unroll
    for (int reg = 0; reg < 4; reg++) {
      float v = lloc[reg];
      v += __shfl_xor(v, 1); v += __shfl_xor(v, 2);
      v += __shfl_xor(v, 4); v += __shfl_xor(v, 8);
      l_i[reg] = l_i[reg] * alpha[reg] + v;
    }
    // rescale O
#pragma unroll
    for (int ht = 0; ht < 8; ht++)
#pragma unroll
      for (int reg = 0; reg < 4; reg++)
        o_acc[ht][reg] = o_acc[ht][reg] * alpha[reg];

    // wave-private P: ensure LDS writes land before reads (in-order LDS + compiler fence)
    __asm__ volatile("s_waitcnt lgkmcnt(0)" ::: "memory");

    // O += P V
#pragma unroll
    for (int ks = 0; ks < 2; ks++) {
      const short8 pa = *(const short8*)(&Ps[wave][r][ks * 32 + q * 8]);
#pragma unroll
      for (int ht = 0; ht < 8; ht++) {
        const short8 vb = *(const short8*)(&Vs[ht * 16 + r][ks * 32 + q * 8]);
        o_acc[ht] = __builtin_amdgcn_mfma_f32_16x16x32_bf16(pa, vb, o_acc[ht], 0, 0, 0);
      }
    }
  }

  // epilogue: O / l
#pragma unroll
  for (int reg = 0; reg < 4; reg++) {
    const float inv_l = 1.0f / l_i[reg];
    const int trow = t0 + wave * 16 + q * 4 + reg;
#pragma unroll
    for (int ht = 0; ht < 8; ht++)
      O[(size_t)trow * NH + n * HDIM + ht * 16 + r] =
          __float2bfloat16(o_acc[ht][reg] * inv_l);
  }
}

// ---------------------------------------------------------------- launch
extern "C" void kernel_launch(void* const* d_in, const int* in_sizes, int n_in,
                              void* d_out, int out_size, void* d_ws, size_t ws_size,
                              hipStream_t stream) {
  (void)in_sizes; (void)n_in; (void)out_size; (void)ws_size;
  const float* x   = (const float*)d_in[0];
  const int* pos   = (const int*)d_in[1];
  const float* w_q = (const float*)d_in[2];
  const float* w_k = (const float*)d_in[3];
  const float* w_v = (const float*)d_in[4];
  const float* w_o = (const float*)d_in[5];
  float* out = (float*)d_out;

  char* ws = (char*)d_ws;
  // byte offsets (16B-aligned by construction); total = 128 MB
  bf16* xb   = (bf16*)(ws);                                  // 2048x4096
  bf16* Bq   = (bf16*)(ws + 16777216ULL);                    // 6144x4096 (later reused for w_o^T)
  bf16* QKV  = (bf16*)(ws + 67108864ULL);                    // 2048x6144
  bf16* Qr   = (bf16*)(ws + 92274688ULL);                    // 2048x4096
  bf16* Kr   = (bf16*)(ws + 109051904ULL);                   // 2048x1024
  bf16* Vt   = (bf16*)(ws + 113246208ULL);                   // 8x128x2048
  bf16* Oatt = (bf16*)(ws + 117440512ULL);                   // 2048x4096
  bf16* woT  = Bq;

  // 1. x -> bf16
  cvt_bf16_kernel<<<(T_SEQ * D_MODEL / 4 + 255) / 256, 256, 0, stream>>>(x, xb, T_SEQ * D_MODEL / 4);
  // 2. W_q/W_k/W_v -> bf16, transposed into stacked B^T (6144 x 4096)
  transpose_cvt<<<dim3(NH / 32, D_MODEL / 32), 256, 0, stream>>>(w_q, Bq, D_MODEL, NH);
  transpose_cvt<<<dim3(KH / 32, D_MODEL / 32), 256, 0, stream>>>(w_k, Bq + (size_t)NH * D_MODEL, D_MODEL, KH);
  transpose_cvt<<<dim3(KH / 32, D_MODEL / 32), 256, 0, stream>>>(w_v, Bq + (size_t)(NH + KH) * D_MODEL, D_MODEL, KH);
  // 3. QKV = xb @ Bq^T   (2048 x 6144)
  gemm_bt<bf16><<<dim3(T_SEQ / 128, QKV_W / 128), 256, 0, stream>>>(xb, Bq, QKV, T_SEQ, QKV_W, D_MODEL);
  // 4. RoPE + split + V transpose
  rope_kernel<<<T_SEQ, 256, 0, stream>>>(QKV, pos, Qr, Kr, Vt);
  // 5. w_o^T (reuses Bq region; stream-ordered after step 3)
  transpose_cvt<<<dim3(D_MODEL / 32, NH / 32), 256, 0, stream>>>(w_o, woT, NH, D_MODEL);
  // 6. causal GQA flash attention
  flash_attn<<<dim3(T_SEQ / 64, N_Q), 256, 0, stream>>>(Qr, Kr, Vt, Oatt);
  // 7. out = Oatt @ woT^T   (2048 x 4096, fp32 out)
  gemm_bt<float><<<dim3(T_SEQ / 128, D_MODEL / 128), 256, 0, stream>>>(Oatt, woT, out, T_SEQ, D_MODEL, NH);
}

// Round 2
// 567.930 us; speedup vs baseline: 1.2995x; 1.2995x over previous
//
#include <hip/hip_runtime.h>
#include <hip/hip_bf16.h>
#include <math.h>

#define T_SEQ   2048
#define D_MODEL 4096
#define N_Q     32
#define N_KV    8
#define HDIM    128
#define NH      (N_Q * HDIM)      // 4096
#define KH      (N_KV * HDIM)     // 1024
#define QKV_W   (NH + 2 * KH)     // 6144

using bf16   = __hip_bfloat16;
using short8 = __attribute__((ext_vector_type(8))) short;
using floatx4 = __attribute__((ext_vector_type(4))) float;

// ---------------------------------------------------------------- helpers
__device__ __forceinline__ void load_lds16(const bf16* g, bf16* l) {
  __builtin_amdgcn_global_load_lds((const __attribute__((address_space(1))) void*)g,
                                   (__attribute__((address_space(3))) void*)l,
                                   16, 0, 0);
}
__device__ __forceinline__ void store_out(bf16* p, float v) { *p = __float2bfloat16(v); }
__device__ __forceinline__ void store_out(float* p, float v) { *p = v; }

// ---------------------------------------------------------------- x -> bf16
__global__ void cvt_bf16_kernel(const float* __restrict__ src, bf16* __restrict__ dst, int n4) {
  int i = blockIdx.x * 256 + threadIdx.x;
  if (i < n4) {
    const float4 v = ((const float4*)src)[i];
    union { bf16 h[4]; unsigned long long u; } o;
    o.h[0] = __float2bfloat16(v.x); o.h[1] = __float2bfloat16(v.y);
    o.h[2] = __float2bfloat16(v.z); o.h[3] = __float2bfloat16(v.w);
    ((unsigned long long*)dst)[i] = o.u;
  }
}

// ------------------------------------------------- fp32 (R,C) -> bf16 (C,R)
__global__ void transpose_cvt(const float* __restrict__ src, bf16* __restrict__ dst,
                              int R, int C) {
  __shared__ float tile[32][33];
  const int bx = blockIdx.x * 32;
  const int by = blockIdx.y * 32;
  const int tx = threadIdx.x & 31, ty = threadIdx.x >> 5;
#pragma unroll
  for (int i = 0; i < 32; i += 8)
    tile[ty + i][tx] = src[(size_t)(by + ty + i) * C + bx + tx];
  __syncthreads();
#pragma unroll
  for (int i = 0; i < 32; i += 8)
    dst[(size_t)(bx + ty + i) * R + by + tx] = __float2bfloat16(tile[tx][ty + i]);
}

// ------------------------------------------------- bf16 (R,C) strided -> bf16 (C,R)
__global__ void transpose_bf16(const bf16* __restrict__ src, bf16* __restrict__ dst,
                               int R, int C, int src_stride) {
  __shared__ bf16 tile[32][33];
  const int bx = blockIdx.x * 32;
  const int by = blockIdx.y * 32;
  const int tx = threadIdx.x & 31, ty = threadIdx.x >> 5;
#pragma unroll
  for (int i = 0; i < 32; i += 8)
    tile[ty + i][tx] = src[(size_t)(by + ty + i) * src_stride + bx + tx];
  __syncthreads();
#pragma unroll
  for (int i = 0; i < 32; i += 8)
    dst[(size_t)(bx + ty + i) * R + by + tx] = tile[tx][ty + i];
}

// ------------------------------------------------- GEMM C[M,N] = A[M,K] * B[N,K]^T
template <typename OutT>
__global__ __launch_bounds__(256)
void gemm_bt(const bf16* __restrict__ A, const bf16* __restrict__ B,
             OutT* __restrict__ C, int M, int N, int Kc) {
  __shared__ bf16 As[128 * 32];
  __shared__ bf16 Bs[128 * 32];
  const int tid  = threadIdx.x;
  const int lane = tid & 63;
  const int wave = tid >> 6;
  const int bm = blockIdx.x * 128;
  const int bn = blockIdx.y * 128;
  const int wm = (wave >> 1) * 64;
  const int wn = (wave & 1) * 64;
  const int r = lane & 15, q = lane >> 4;

  floatx4 acc[4][4];
  const floatx4 zero = {0.f, 0.f, 0.f, 0.f};
#pragma unroll
  for (int i = 0; i < 4; i++)
#pragma unroll
    for (int j = 0; j < 4; j++) acc[i][j] = zero;

  const int srow = wave * 32 + (lane >> 2);
  const int scol = (lane & 3) * 8;
  const bf16* gA = A + (size_t)(bm + srow) * Kc + scol;
  const bf16* gB = B + (size_t)(bn + srow) * Kc + scol;
  bf16* lA = As + wave * 32 * 32;
  bf16* lB = Bs + wave * 32 * 32;

  for (int k0 = 0; k0 < Kc; k0 += 32) {
    __syncthreads();
    load_lds16(gA + k0,                   lA);
    load_lds16(gA + k0 + 16 * (size_t)Kc, lA + 16 * 32);
    load_lds16(gB + k0,                   lB);
    load_lds16(gB + k0 + 16 * (size_t)Kc, lB + 16 * 32);
    __syncthreads();

    short8 af[4], bfr[4];
#pragma unroll
    for (int mt = 0; mt < 4; mt++)
      af[mt] = *(const short8*)(As + (wm + mt * 16 + r) * 32 + q * 8);
#pragma unroll
    for (int nt = 0; nt < 4; nt++)
      bfr[nt] = *(const short8*)(Bs + (wn + nt * 16 + r) * 32 + q * 8);
#pragma unroll
    for (int mt = 0; mt < 4; mt++)
#pragma unroll
      for (int nt = 0; nt < 4; nt++)
        acc[mt][nt] = __builtin_amdgcn_mfma_f32_16x16x32_bf16(af[mt], bfr[nt], acc[mt][nt], 0, 0, 0);
  }

#pragma unroll
  for (int mt = 0; mt < 4; mt++)
#pragma unroll
    for (int nt = 0; nt < 4; nt++)
#pragma unroll
      for (int reg = 0; reg < 4; reg++) {
        const int row = bm + wm + mt * 16 + q * 4 + reg;
        const int col = bn + wn + nt * 16 + r;
        store_out(&C[(size_t)row * N + col], acc[mt][nt][reg]);
      }
}

// ------------------------------------------------- RoPE (Q pre-scaled by 1/sqrt(H)*log2e)
__global__ void rope_kernel(const bf16* __restrict__ QKV, const int* __restrict__ positions,
                            bf16* __restrict__ Q, bf16* __restrict__ Kr) {
  const int t = blockIdx.x;
  const float pos = (float)positions[t];
  const int hh = threadIdx.x & 63;
  // inv_freq = 10000^(-hh/64) = exp2(-hh * log2(1e4)/64)
  const float inv = exp2f(-(float)hh * 0.2076205092954967f);
  float sn, cs; sincosf(pos * inv, &sn, &cs);
  const float SCL = 0.12751744868673310f;  // 1/sqrt(128) * log2(e)
  const bf16* row = QKV + (size_t)t * QKV_W;
  for (int idx = threadIdx.x; idx < N_Q * 64; idx += 256) {
    const int n = idx >> 6;
    const float x1 = __bfloat162float(row[n * HDIM + hh]);
    const float x2 = __bfloat162float(row[n * HDIM + hh + 64]);
    Q[(size_t)t * NH + n * HDIM + hh]      = __float2bfloat16((x1 * cs - x2 * sn) * SCL);
    Q[(size_t)t * NH + n * HDIM + hh + 64] = __float2bfloat16((x2 * cs + x1 * sn) * SCL);
  }
  for (int idx = threadIdx.x; idx < N_KV * 64; idx += 256) {
    const int kh = idx >> 6;
    const float x1 = __bfloat162float(row[NH + kh * HDIM + hh]);
    const float x2 = __bfloat162float(row[NH + kh * HDIM + hh + 64]);
    Kr[(size_t)t * KH + kh * HDIM + hh]      = __float2bfloat16(x1 * cs - x2 * sn);
    Kr[(size_t)t * KH + kh * HDIM + hh + 64] = __float2bfloat16(x2 * cs + x1 * sn);
  }
}

// ------------------------------------------------- causal GQA flash attention v2
// Block: 128 q rows (4 waves x 32 rows, two 16-row M-frags each), 64-col kv tiles.
// Grid 512 = 2 blocks/CU; ids paired (big, small) so per-CU work is constant (34 iters).
__global__ __launch_bounds__(256, 2)
void flash_attn(const bf16* __restrict__ Q, const bf16* __restrict__ Kk,
                const bf16* __restrict__ Vt, bf16* __restrict__ O) {
  const int id = blockIdx.x;
  const int n  = id & 31;
  const int kh = n >> 2;
  const int bt = (id < 256) ? (15 - (id >> 5)) : ((id - 256) >> 5);
  const int t0 = bt * 128;
  const int tid = threadIdx.x, lane = tid & 63, w = tid >> 6;
  const int r = lane & 15, q = lane >> 4;

  __shared__ bf16 Ks[64][128];     // [s][h], XOR-swizzled 16B chunks
  __shared__ bf16 Vs[128][64];     // [h][s], XOR-swizzled 16B chunks
  __shared__ bf16 Ps[4][32][72];   // per-wave P, padded

  // Q fragments: wave w owns rows t0 + w*32 .. +31 (two 16-row frags)
  short8 qf[2][4];
#pragma unroll
  for (int mf = 0; mf < 2; mf++) {
    const bf16* qrow = Q + (size_t)(t0 + w * 32 + mf * 16 + r) * NH + n * HDIM;
#pragma unroll
    for (int ks = 0; ks < 4; ks++)
      qf[mf][ks] = *(const short8*)(qrow + ks * 32 + q * 8);
  }

  floatx4 o_acc[2][8];
  const floatx4 zero = {0.f, 0.f, 0.f, 0.f};
#pragma unroll
  for (int mf = 0; mf < 2; mf++)
#pragma unroll
    for (int i = 0; i < 8; i++) o_acc[mf][i] = zero;
  float m_i[2][4], l_i[2][4];
#pragma unroll
  for (int mf = 0; mf < 2; mf++)
#pragma unroll
    for (int i = 0; i < 4; i++) { m_i[mf][i] = -INFINITY; l_i[mf][i] = 0.f; }

  const int nIter = 2 * bt + 2;
  for (int it = 0; it < nIter; ++it) {
    const int s0 = it * 64;
    __syncthreads();
    // stage K tile (64 s x 128 h) with chunk swizzle
#pragma unroll
    for (int c = 0; c < 4; c++) {
      const int chunk = tid + 256 * c;
      const int s = chunk >> 4, cx = chunk & 15;
      *(short8*)(&Ks[s][(cx ^ (s & 7)) * 8]) =
          *(const short8*)(Kk + (size_t)(s0 + s) * KH + kh * HDIM + cx * 8);
    }
    // stage V^T tile (128 h x 64 s) with chunk swizzle
#pragma unroll
    for (int c = 0; c < 4; c++) {
      const int chunk = tid + 256 * c;
      const int h = chunk >> 3, sc = chunk & 7;
      *(short8*)(&Vs[h][(sc ^ (h & 7)) * 8]) =
          *(const short8*)(Vt + ((size_t)kh * HDIM + h) * T_SEQ + s0 + sc * 8);
    }
    __syncthreads();

    // S = Q K^T : per wave 32 q-rows x 64 kv-cols
    floatx4 sa[2][4];
#pragma unroll
    for (int mf = 0; mf < 2; mf++)
#pragma unroll
      for (int nt = 0; nt < 4; nt++) sa[mf][nt] = zero;
#pragma unroll
    for (int ks = 0; ks < 4; ks++)
#pragma unroll
      for (int nt = 0; nt < 4; nt++) {
        const int krow = nt * 16 + r;
        const short8 kb = *(const short8*)(&Ks[krow][(((ks * 4 + q) ^ (krow & 7))) * 8]);
#pragma unroll
        for (int mf = 0; mf < 2; mf++)
          sa[mf][nt] = __builtin_amdgcn_mfma_f32_16x16x32_bf16(qf[mf][ks], kb, sa[mf][nt], 0, 0, 0);
      }

#pragma unroll
    for (int mf = 0; mf < 2; mf++) {
      const int rbase = t0 + w * 32 + mf * 16;     // + q*4 + reg
      // causal mask (scores already in log2 units)
      if (s0 + 63 > rbase) {
#pragma unroll
        for (int nt = 0; nt < 4; nt++)
#pragma unroll
          for (int reg = 0; reg < 4; reg++) {
            const int trow = rbase + q * 4 + reg;
            const int scol = s0 + nt * 16 + r;
            if (scol > trow) sa[mf][nt][reg] = -INFINITY;
          }
      }
      float mloc[4];
#pragma unroll
      for (int reg = 0; reg < 4; reg++) {
        float v = fmaxf(fmaxf(sa[mf][0][reg], sa[mf][1][reg]),
                        fmaxf(sa[mf][2][reg], sa[mf][3][reg]));
        v = fmaxf(v, __shfl_xor(v, 1));
        v = fmaxf(v, __shfl_xor(v, 2));
        v = fmaxf(v, __shfl_xor(v, 4));
        v = fmaxf(v, __shfl_xor(v, 8));
        mloc[reg] = v;
      }
      float alpha[4], lloc[4];
#pragma unroll
      for (int reg = 0; reg < 4; reg++) {
        const float mnew = fmaxf(m_i[mf][reg], mloc[reg]);
        alpha[reg] = exp2f(m_i[mf][reg] - mnew);
        m_i[mf][reg] = mnew;
        lloc[reg] = 0.f;
      }
#pragma unroll
      for (int nt = 0; nt < 4; nt++)
#pragma unroll
        for (int reg = 0; reg < 4; reg++) {
          const float p = exp2f(sa[mf][nt][reg] - m_i[mf][reg]);
          lloc[reg] += p;
          Ps[w][mf * 16 + q * 4 + reg][nt * 16 + r] = __float2bfloat16(p);
        }
#pragma unroll
      for (int reg = 0; reg < 4; reg++) {
        float v = lloc[reg];
        v += __shfl_xor(v, 1); v += __shfl_xor(v, 2);
        v += __shfl_xor(v, 4); v += __shfl_xor(v, 8);
        l_i[mf][reg] = l_i[mf][reg] * alpha[reg] + v;
      }
#pragma unroll
      for (int ht = 0; ht < 8; ht++)
#pragma unroll
        for (int reg = 0; reg < 4; reg++)
          o_acc[mf][ht][reg] *= alpha[reg];
    }

    // wave-private P: drain LDS writes before reads
    __asm__ volatile("s_waitcnt lgkmcnt(0)" ::: "memory");

    // O += P V
#pragma unroll
    for (int ks = 0; ks < 2; ks++) {
      short8 pa[2];
#pragma unroll
      for (int mf = 0; mf < 2; mf++)
        pa[mf] = *(const short8*)(&Ps[w][mf * 16 + r][ks * 32 + q * 8]);
#pragma unroll
      for (int ht = 0; ht < 8; ht++) {
        const int vrow = ht * 16 + r;
        const short8 vb = *(const short8*)(&Vs[vrow][(((ks * 4 + q) ^ (vrow & 7))) * 8]);
#pragma unroll
        for (int mf = 0; mf < 2; mf++)
          o_acc[mf][ht] = __builtin_amdgcn_mfma_f32_16x16x32_bf16(pa[mf], vb, o_acc[mf][ht], 0, 0, 0);
      }
    }
  }

  // epilogue
#pragma unroll
  for (int mf = 0; mf < 2; mf++)
#pragma unroll
    for (int reg = 0; reg < 4; reg++) {
      const float inv_l = 1.0f / l_i[mf][reg];
      const int trow = t0 + w * 32 + mf * 16 + q * 4 + reg;
#pragma unroll
      for (int ht = 0; ht < 8; ht++)
        O[(size_t)trow * NH + n * HDIM + ht * 16 + r] =
            __float2bfloat16(o_acc[mf][ht][reg] * inv_l);
    }
}

// ---------------------------------------------------------------- launch
extern "C" void kernel_launch(void* const* d_in, const int* in_sizes, int n_in,
                              void* d_out, int out_size, void* d_ws, size_t ws_size,
                              hipStream_t stream) {
  (void)in_sizes; (void)n_in; (void)out_size; (void)ws_size;
  const float* x   = (const float*)d_in[0];
  const int* pos   = (const int*)d_in[1];
  const float* w_q = (const float*)d_in[2];
  const float* w_k = (const float*)d_in[3];
  const float* w_v = (const float*)d_in[4];
  const float* w_o = (const float*)d_in[5];
  float* out = (float*)d_out;

  char* ws = (char*)d_ws;
  bf16* xb   = (bf16*)(ws);                                  // 2048x4096
  bf16* Bq   = (bf16*)(ws + 16777216ULL);                    // 6144x4096 (later reused for w_o^T)
  bf16* QKV  = (bf16*)(ws + 67108864ULL);                    // 2048x6144
  bf16* Qr   = (bf16*)(ws + 92274688ULL);                    // 2048x4096
  bf16* Kr   = (bf16*)(ws + 109051904ULL);                   // 2048x1024
  bf16* Vt   = (bf16*)(ws + 113246208ULL);                   // 8x128x2048 = (KH x T)
  bf16* Oatt = (bf16*)(ws + 117440512ULL);                   // 2048x4096
  bf16* woT  = Bq;

  cvt_bf16_kernel<<<(T_SEQ * D_MODEL / 4 + 255) / 256, 256, 0, stream>>>(x, xb, T_SEQ * D_MODEL / 4);
  transpose_cvt<<<dim3(NH / 32, D_MODEL / 32), 256, 0, stream>>>(w_q, Bq, D_MODEL, NH);
  transpose_cvt<<<dim3(KH / 32, D_MODEL / 32), 256, 0, stream>>>(w_k, Bq + (size_t)NH * D_MODEL, D_MODEL, KH);
  transpose_cvt<<<dim3(KH / 32, D_MODEL / 32), 256, 0, stream>>>(w_v, Bq + (size_t)(NH + KH) * D_MODEL, D_MODEL, KH);
  gemm_bt<bf16><<<dim3(T_SEQ / 128, QKV_W / 128), 256, 0, stream>>>(xb, Bq, QKV, T_SEQ, QKV_W, D_MODEL);
  rope_kernel<<<T_SEQ, 256, 0, stream>>>(QKV, pos, Qr, Kr);
  // V^T: (T x KH) slice of QKV -> (KH x T), coalesced tile transpose
  transpose_bf16<<<dim3(KH / 32, T_SEQ / 32), 256, 0, stream>>>(QKV + NH + KH, Vt, T_SEQ, KH, QKV_W);
  transpose_cvt<<<dim3(D_MODEL / 32, NH / 32), 256, 0, stream>>>(w_o, woT, NH, D_MODEL);
  flash_attn<<<dim3(512), 256, 0, stream>>>(Qr, Kr, Vt, Oatt);
  gemm_bt<float><<<dim3(T_SEQ / 128, D_MODEL / 128), 256, 0, stream>>>(Oatt, woT, out, T_SEQ, D_MODEL, NH);
}

// Round 3
// 533.936 us; speedup vs baseline: 1.3822x; 1.0637x over previous
//
#include <hip/hip_runtime.h>
#include <hip/hip_bf16.h>
#include <math.h>

#define T_SEQ   2048
#define D_MODEL 4096
#define N_Q     32
#define N_KV    8
#define HDIM    128
#define NH      (N_Q * HDIM)      // 4096
#define KH      (N_KV * HDIM)     // 1024
#define QKV_W   (NH + 2 * KH)     // 6144

using bf16   = __hip_bfloat16;
using short8 = __attribute__((ext_vector_type(8))) short;
using floatx4 = __attribute__((ext_vector_type(4))) float;

// ---------------------------------------------------------------- helpers
__device__ __forceinline__ void load_lds16(const bf16* g, bf16* l) {
  __builtin_amdgcn_global_load_lds((const __attribute__((address_space(1))) void*)g,
                                   (__attribute__((address_space(3))) void*)l,
                                   16, 0, 0);
}

// ---------------------------------------------------------------- x -> bf16
__global__ void cvt_bf16_kernel(const float* __restrict__ src, bf16* __restrict__ dst, int n4) {
  int i = blockIdx.x * 256 + threadIdx.x;
  if (i < n4) {
    const float4 v = ((const float4*)src)[i];
    union { bf16 h[4]; unsigned long long u; } o;
    o.h[0] = __float2bfloat16(v.x); o.h[1] = __float2bfloat16(v.y);
    o.h[2] = __float2bfloat16(v.z); o.h[3] = __float2bfloat16(v.w);
    ((unsigned long long*)dst)[i] = o.u;
  }
}

// ------------------------------------------------- fp32 (R,C) -> bf16 (C,R), 64x64 tiles
__global__ __launch_bounds__(256)
void transpose_cvt(const float* __restrict__ src, bf16* __restrict__ dst, int R, int C) {
  __shared__ float tile[64][65];
  const int bx = blockIdx.x * 64;   // src col base
  const int by = blockIdx.y * 64;   // src row base
  const int c4 = (threadIdx.x & 15) * 4;
  const int r0 = threadIdx.x >> 4;  // 0..15
#pragma unroll
  for (int i = 0; i < 4; i++) {
    const float4 v = *(const float4*)&src[(size_t)(by + r0 + i * 16) * C + bx + c4];
    tile[r0 + i * 16][c4 + 0] = v.x;
    tile[r0 + i * 16][c4 + 1] = v.y;
    tile[r0 + i * 16][c4 + 2] = v.z;
    tile[r0 + i * 16][c4 + 3] = v.w;
  }
  __syncthreads();
  const int cc = threadIdx.x >> 2;        // 0..63
  const int rq = (threadIdx.x & 3) * 16;  // 0,16,32,48
  union { bf16 h[8]; short8 s; } o0, o1;
#pragma unroll
  for (int j = 0; j < 8; j++) {
    o0.h[j] = __float2bfloat16(tile[rq + j][cc]);
    o1.h[j] = __float2bfloat16(tile[rq + 8 + j][cc]);
  }
  bf16* d = dst + (size_t)(bx + cc) * R + by + rq;
  *(short8*)(d)     = o0.s;
  *(short8*)(d + 8) = o1.s;
}

// ------------------------------------------------- GEMM v2: C[M,N] = A[M,K]*B[N,K]^T
// 128x128 tile, BK=64, XOR-swizzled LDS chunks (conflict-free frag reads).
// EPI=1: store fp32 C. EPI=2: fused rope/split epilogue (QKV producer).
#define CS_STRIDE 137
template <int EPI>
__global__ __launch_bounds__(256)
void gemm_bt2(const bf16* __restrict__ A, const bf16* __restrict__ B,
              float* __restrict__ Cf, int N, int Kc,
              const int* __restrict__ positions,
              bf16* __restrict__ Qo, bf16* __restrict__ Ko, bf16* __restrict__ Vo) {
  __shared__ bf16 smem[(EPI == 2) ? (128 * CS_STRIDE) : (128 * 128)];
  bf16* As = smem;
  bf16* Bs = smem + 128 * 64;

  const int tid  = threadIdx.x;
  const int lane = tid & 63;
  const int wave = tid >> 6;
  const int bm = blockIdx.x * 128;
  const int bn = blockIdx.y * 128;
  const int wm = (wave >> 1) * 64;
  const int wn = (wave & 1) * 64;
  const int r = lane & 15, q = lane >> 4;

  floatx4 acc[4][4];
  const floatx4 zero = {0.f, 0.f, 0.f, 0.f};
#pragma unroll
  for (int i = 0; i < 4; i++)
#pragma unroll
    for (int j = 0; j < 4; j++) acc[i][j] = zero;

  // staging roles: 8 lanes per row, chunk XOR-swizzled within the 128B row line
  const int rl = lane >> 3, ch = lane & 7;
  const int srow = wave * 32 + rl;             // +i*8
  const int gch = ch ^ rl;
  const bf16* gA = A + (size_t)(bm + srow) * Kc + gch * 8;
  const bf16* gB = B + (size_t)(bn + srow) * Kc + gch * 8;

  for (int k0 = 0; k0 < Kc; k0 += 64) {
    __syncthreads();
#pragma unroll
    for (int i = 0; i < 4; i++)
      load_lds16(gA + k0 + (size_t)i * 8 * Kc, As + (wave * 32 + i * 8) * 64);
#pragma unroll
    for (int i = 0; i < 4; i++)
      load_lds16(gB + k0 + (size_t)i * 8 * Kc, Bs + (wave * 32 + i * 8) * 64);
    __syncthreads();

#pragma unroll
    for (int ks = 0; ks < 2; ks++) {
      short8 af[4], bfr[4];
#pragma unroll
      for (int mt = 0; mt < 4; mt++)
        af[mt] = *(const short8*)(As + (wm + mt * 16 + r) * 64 + ((ks * 4 + q) ^ (r & 7)) * 8);
#pragma unroll
      for (int nt = 0; nt < 4; nt++)
        bfr[nt] = *(const short8*)(Bs + (wn + nt * 16 + r) * 64 + ((ks * 4 + q) ^ (r & 7)) * 8);
#pragma unroll
      for (int mt = 0; mt < 4; mt++)
#pragma unroll
        for (int nt = 0; nt < 4; nt++)
          acc[mt][nt] = __builtin_amdgcn_mfma_f32_16x16x32_bf16(af[mt], bfr[nt], acc[mt][nt], 0, 0, 0);
    }
  }

  if (EPI == 1) {
#pragma unroll
    for (int mt = 0; mt < 4; mt++)
#pragma unroll
      for (int nt = 0; nt < 4; nt++)
#pragma unroll
        for (int reg = 0; reg < 4; reg++) {
          const int row = bm + wm + mt * 16 + q * 4 + reg;
          const int col = bn + wn + nt * 16 + r;
          Cf[(size_t)row * N + col] = acc[mt][nt][reg];
        }
  } else {
    // ---- fused rope/split epilogue: this block owns one head (hn = blockIdx.y)
    __syncthreads();   // all waves done reading As/Bs before aliasing with Cs
#pragma unroll
    for (int mt = 0; mt < 4; mt++)
#pragma unroll
      for (int nt = 0; nt < 4; nt++)
#pragma unroll
        for (int reg = 0; reg < 4; reg++)
          smem[(wm + mt * 16 + q * 4 + reg) * CS_STRIDE + wn + nt * 16 + r] =
              __float2bfloat16(acc[mt][nt][reg]);
    __syncthreads();

    const int hn = blockIdx.y;
    if (hn < N_Q + N_KV) {
      // Q or K head: rope
      const float SCL = 0.12751744868673310f;  // 1/sqrt(128) * log2(e), Q only
      const bool isQ = (hn < N_Q);
      bf16* base = isQ ? (Qo + (size_t)bm * NH + hn * HDIM)
                       : (Ko + (size_t)bm * KH + (hn - N_Q) * HDIM);
      const int ostride = isQ ? NH : KH;
      for (int idx = tid; idx < 128 * 64; idx += 256) {
        const int row = idx >> 6, h = idx & 63;
        const float x1 = __bfloat162float(smem[row * CS_STRIDE + h]);
        const float x2 = __bfloat162float(smem[row * CS_STRIDE + h + 64]);
        const float pos = (float)positions[bm + row];
        const float inv = exp2f(-(float)h * 0.20762050593046013f);
        float sn, cs; sincosf(pos * inv, &sn, &cs);
        float o1 = x1 * cs - x2 * sn;
        float o2 = x2 * cs + x1 * sn;
        if (isQ) { o1 *= SCL; o2 *= SCL; }
        bf16* d = base + (size_t)row * ostride;
        d[h]      = __float2bfloat16(o1);
        d[h + 64] = __float2bfloat16(o2);
      }
    } else {
      // V head: write V^T (KH x T)
      const int kh = hn - (N_Q + N_KV);
      for (int idx = tid; idx < 128 * 32; idx += 256) {
        const int h = idx >> 5, r4 = (idx & 31) * 4;
        union { bf16 h4[4]; unsigned long long u; } o;
#pragma unroll
        for (int j = 0; j < 4; j++) o.h4[j] = smem[(r4 + j) * CS_STRIDE + h];
        *(unsigned long long*)(Vo + ((size_t)kh * HDIM + h) * T_SEQ + bm + r4) = o.u;
      }
    }
  }
}

// ------------------------------------------------- causal GQA flash attention
// Block: 128 q rows (4 waves x 32 rows), 64-col kv tiles; grid 512 = 2/CU,
// paired big/small bt so per-CU work is constant.
__global__ __launch_bounds__(256, 2)
void flash_attn(const bf16* __restrict__ Q, const bf16* __restrict__ Kk,
                const bf16* __restrict__ Vt, bf16* __restrict__ O) {
  const int id = blockIdx.x;
  const int n  = id & 31;
  const int kh = n >> 2;
  const int bt = (id < 256) ? (15 - (id >> 5)) : ((id - 256) >> 5);
  const int t0 = bt * 128;
  const int tid = threadIdx.x, lane = tid & 63, w = tid >> 6;
  const int r = lane & 15, q = lane >> 4;

  __shared__ bf16 Ks[64][128];     // [s][h], XOR-swizzled 16B chunks
  __shared__ bf16 Vs[128][64];     // [h][s], XOR-swizzled 16B chunks
  __shared__ bf16 Ps[4][32][72];   // per-wave P, padded

  short8 qf[2][4];
#pragma unroll
  for (int mf = 0; mf < 2; mf++) {
    const bf16* qrow = Q + (size_t)(t0 + w * 32 + mf * 16 + r) * NH + n * HDIM;
#pragma unroll
    for (int ks = 0; ks < 4; ks++)
      qf[mf][ks] = *(const short8*)(qrow + ks * 32 + q * 8);
  }

  floatx4 o_acc[2][8];
  const floatx4 zero = {0.f, 0.f, 0.f, 0.f};
#pragma unroll
  for (int mf = 0; mf < 2; mf++)
#pragma unroll
    for (int i = 0; i < 8; i++) o_acc[mf][i] = zero;
  float m_i[2][4], l_i[2][4];
#pragma unroll
  for (int mf = 0; mf < 2; mf++)
#pragma unroll
    for (int i = 0; i < 4; i++) { m_i[mf][i] = -INFINITY; l_i[mf][i] = 0.f; }

  const int nIter = 2 * bt + 2;
  for (int it = 0; it < nIter; ++it) {
    const int s0 = it * 64;
    __syncthreads();
#pragma unroll
    for (int c = 0; c < 4; c++) {
      const int chunk = tid + 256 * c;
      const int s = chunk >> 4, cx = chunk & 15;
      *(short8*)(&Ks[s][(cx ^ (s & 7)) * 8]) =
          *(const short8*)(Kk + (size_t)(s0 + s) * KH + kh * HDIM + cx * 8);
    }
#pragma unroll
    for (int c = 0; c < 4; c++) {
      const int chunk = tid + 256 * c;
      const int h = chunk >> 3, sc = chunk & 7;
      *(short8*)(&Vs[h][(sc ^ (h & 7)) * 8]) =
          *(const short8*)(Vt + ((size_t)kh * HDIM + h) * T_SEQ + s0 + sc * 8);
    }
    __syncthreads();

    floatx4 sa[2][4];
#pragma unroll
    for (int mf = 0; mf < 2; mf++)
#pragma unroll
      for (int nt = 0; nt < 4; nt++) sa[mf][nt] = zero;
#pragma unroll
    for (int ks = 0; ks < 4; ks++)
#pragma unroll
      for (int nt = 0; nt < 4; nt++) {
        const int krow = nt * 16 + r;
        const short8 kb = *(const short8*)(&Ks[krow][(((ks * 4 + q) ^ (krow & 7))) * 8]);
#pragma unroll
        for (int mf = 0; mf < 2; mf++)
          sa[mf][nt] = __builtin_amdgcn_mfma_f32_16x16x32_bf16(qf[mf][ks], kb, sa[mf][nt], 0, 0, 0);
      }

#pragma unroll
    for (int mf = 0; mf < 2; mf++) {
      const int rbase = t0 + w * 32 + mf * 16;
      if (s0 + 63 > rbase) {
#pragma unroll
        for (int nt = 0; nt < 4; nt++)
#pragma unroll
          for (int reg = 0; reg < 4; reg++) {
            const int trow = rbase + q * 4 + reg;
            const int scol = s0 + nt * 16 + r;
            if (scol > trow) sa[mf][nt][reg] = -INFINITY;
          }
      }
      float mloc[4];
#pragma unroll
      for (int reg = 0; reg < 4; reg++) {
        float v = fmaxf(fmaxf(sa[mf][0][reg], sa[mf][1][reg]),
                        fmaxf(sa[mf][2][reg], sa[mf][3][reg]));
        v = fmaxf(v, __shfl_xor(v, 1));
        v = fmaxf(v, __shfl_xor(v, 2));
        v = fmaxf(v, __shfl_xor(v, 4));
        v = fmaxf(v, __shfl_xor(v, 8));
        mloc[reg] = v;
      }
      float alpha[4], lloc[4];
#pragma unroll
      for (int reg = 0; reg < 4; reg++) {
        const float mnew = fmaxf(m_i[mf][reg], mloc[reg]);
        alpha[reg] = exp2f(m_i[mf][reg] - mnew);
        m_i[mf][reg] = mnew;
        lloc[reg] = 0.f;
      }
#pragma unroll
      for (int nt = 0; nt < 4; nt++)
#pragma unroll
        for (int reg = 0; reg < 4; reg++) {
          const float p = exp2f(sa[mf][nt][reg] - m_i[mf][reg]);
          lloc[reg] += p;
          Ps[w][mf * 16 + q * 4 + reg][nt * 16 + r] = __float2bfloat16(p);
        }
#pragma unroll
      for (int reg = 0; reg < 4; reg++) {
        float v = lloc[reg];
        v += __shfl_xor(v, 1); v += __shfl_xor(v, 2);
        v += __shfl_xor(v, 4); v += __shfl_xor(v, 8);
        l_i[mf][reg] = l_i[mf][reg] * alpha[reg] + v;
      }
#pragma unroll
      for (int ht = 0; ht < 8; ht++)
#pragma unroll
        for (int reg = 0; reg < 4; reg++)
          o_acc[mf][ht][reg] *= alpha[reg];
    }

    __asm__ volatile("s_waitcnt lgkmcnt(0)" ::: "memory");

#pragma unroll
    for (int ks = 0; ks < 2; ks++) {
      short8 pa[2];
#pragma unroll
      for (int mf = 0; mf < 2; mf++)
        pa[mf] = *(const short8*)(&Ps[w][mf * 16 + r][ks * 32 + q * 8]);
#pragma unroll
      for (int ht = 0; ht < 8; ht++) {
        const int vrow = ht * 16 + r;
        const short8 vb = *(const short8*)(&Vs[vrow][(((ks * 4 + q) ^ (vrow & 7))) * 8]);
#pragma unroll
        for (int mf = 0; mf < 2; mf++)
          o_acc[mf][ht] = __builtin_amdgcn_mfma_f32_16x16x32_bf16(pa[mf], vb, o_acc[mf][ht], 0, 0, 0);
      }
    }
  }

#pragma unroll
  for (int mf = 0; mf < 2; mf++)
#pragma unroll
    for (int reg = 0; reg < 4; reg++) {
      const float inv_l = 1.0f / l_i[mf][reg];
      const int trow = t0 + w * 32 + mf * 16 + q * 4 + reg;
#pragma unroll
      for (int ht = 0; ht < 8; ht++)
        O[(size_t)trow * NH + n * HDIM + ht * 16 + r] =
            __float2bfloat16(o_acc[mf][ht][reg] * inv_l);
    }
}

// ---------------------------------------------------------------- launch
extern "C" void kernel_launch(void* const* d_in, const int* in_sizes, int n_in,
                              void* d_out, int out_size, void* d_ws, size_t ws_size,
                              hipStream_t stream) {
  (void)in_sizes; (void)n_in; (void)out_size; (void)ws_size;
  const float* x   = (const float*)d_in[0];
  const int* pos   = (const int*)d_in[1];
  const float* w_q = (const float*)d_in[2];
  const float* w_k = (const float*)d_in[3];
  const float* w_v = (const float*)d_in[4];
  const float* w_o = (const float*)d_in[5];
  float* out = (float*)d_out;

  char* ws = (char*)d_ws;
  bf16* xb   = (bf16*)(ws);                       // 2048x4096          @ 0
  bf16* Bq   = (bf16*)(ws + (16ULL << 20));       // 6144x4096          @ 16M (reused for w_o^T)
  bf16* Qr   = (bf16*)(ws + (64ULL << 20));       // 2048x4096          @ 64M
  bf16* Kr   = (bf16*)(ws + (80ULL << 20));       // 2048x1024          @ 80M
  bf16* Vt   = (bf16*)(ws + (84ULL << 20));       // (8*128) x 2048     @ 84M
  bf16* Oatt = (bf16*)(ws + (88ULL << 20));       // 2048x4096          @ 88M
  bf16* woT  = Bq;

  cvt_bf16_kernel<<<(T_SEQ * D_MODEL / 4 + 255) / 256, 256, 0, stream>>>(x, xb, T_SEQ * D_MODEL / 4);
  transpose_cvt<<<dim3(NH / 64, D_MODEL / 64), 256, 0, stream>>>(w_q, Bq, D_MODEL, NH);
  transpose_cvt<<<dim3(KH / 64, D_MODEL / 64), 256, 0, stream>>>(w_k, Bq + (size_t)NH * D_MODEL, D_MODEL, KH);
  transpose_cvt<<<dim3(KH / 64, D_MODEL / 64), 256, 0, stream>>>(w_v, Bq + (size_t)(NH + KH) * D_MODEL, D_MODEL, KH);

  // fused QKV GEMM + rope/split epilogue
  gemm_bt2<2><<<dim3(T_SEQ / 128, QKV_W / 128), 256, 0, stream>>>(
      xb, Bq, nullptr, QKV_W, D_MODEL, pos, Qr, Kr, Vt);

  // w_o^T (reuses Bq region; stream-ordered after the QKV GEMM)
  transpose_cvt<<<dim3(D_MODEL / 64, NH / 64), 256, 0, stream>>>(w_o, woT, NH, D_MODEL);

  flash_attn<<<dim3(512), 256, 0, stream>>>(Qr, Kr, Vt, Oatt);

  gemm_bt2<1><<<dim3(T_SEQ / 128, D_MODEL / 128), 256, 0, stream>>>(
      Oatt, woT, out, D_MODEL, NH, nullptr, nullptr, nullptr, nullptr);
}

// Round 4
// 506.441 us; speedup vs baseline: 1.4572x; 1.0543x over previous
//
#include <hip/hip_runtime.h>
#include <hip/hip_bf16.h>
#include <math.h>

#define T_SEQ   2048
#define D_MODEL 4096
#define N_Q     32
#define N_KV    8
#define HDIM    128
#define NH      (N_Q * HDIM)      // 4096
#define KH      (N_KV * HDIM)     // 1024
#define QKV_W   (NH + 2 * KH)     // 6144

using bf16   = __hip_bfloat16;
using short8 = __attribute__((ext_vector_type(8))) short;
using floatx4 = __attribute__((ext_vector_type(4))) float;

// ---------------------------------------------------------------- helpers
__device__ __forceinline__ void load_lds16(const bf16* g, bf16* l) {
  __builtin_amdgcn_global_load_lds((const __attribute__((address_space(1))) void*)g,
                                   (__attribute__((address_space(3))) void*)l,
                                   16, 0, 0);
}

// ---------------------------------------------------------------- x -> bf16
__global__ void cvt_bf16_kernel(const float* __restrict__ src, bf16* __restrict__ dst, int n4) {
  int i = blockIdx.x * 256 + threadIdx.x;
  if (i < n4) {
    const float4 v = ((const float4*)src)[i];
    union { bf16 h[4]; unsigned long long u; } o;
    o.h[0] = __float2bfloat16(v.x); o.h[1] = __float2bfloat16(v.y);
    o.h[2] = __float2bfloat16(v.z); o.h[3] = __float2bfloat16(v.w);
    ((unsigned long long*)dst)[i] = o.u;
  }
}

// ---------------------------------------------------------------- sincos table [t][64]
__global__ void sincos_tab(const int* __restrict__ pos, float* __restrict__ ct,
                           float* __restrict__ st) {
  const int i = blockIdx.x * 256 + threadIdx.x;   // t*64 + h
  const int t = i >> 6, h = i & 63;
  const float p = (float)pos[t];
  const float inv = exp2f(-(float)h * 0.20762050592420985f);  // log2(1e4)/64
  float s, c; sincosf(p * inv, &s, &c);
  ct[i] = c; st[i] = s;
}

// ------------------------------------------------- fp32 (R,C) -> bf16 (C,R), 64x64 tiles
__global__ __launch_bounds__(256)
void transpose_cvt(const float* __restrict__ src, bf16* __restrict__ dst, int R, int C) {
  __shared__ float tile[64][65];
  const int bx = blockIdx.x * 64;   // src col base
  const int by = blockIdx.y * 64;   // src row base
  const int c4 = (threadIdx.x & 15) * 4;
  const int r0 = threadIdx.x >> 4;  // 0..15
#pragma unroll
  for (int i = 0; i < 4; i++) {
    const float4 v = *(const float4*)&src[(size_t)(by + r0 + i * 16) * C + bx + c4];
    tile[r0 + i * 16][c4 + 0] = v.x;
    tile[r0 + i * 16][c4 + 1] = v.y;
    tile[r0 + i * 16][c4 + 2] = v.z;
    tile[r0 + i * 16][c4 + 3] = v.w;
  }
  __syncthreads();
  const int cc = threadIdx.x >> 2;        // 0..63
  const int rq = (threadIdx.x & 3) * 16;  // 0,16,32,48
  union { bf16 h[8]; short8 s; } o0, o1;
#pragma unroll
  for (int j = 0; j < 8; j++) {
    o0.h[j] = __float2bfloat16(tile[rq + j][cc]);
    o1.h[j] = __float2bfloat16(tile[rq + 8 + j][cc]);
  }
  bf16* d = dst + (size_t)(bx + cc) * R + by + rq;
  *(short8*)(d)     = o0.s;
  *(short8*)(d + 8) = o1.s;
}

// ------------------------------------------------- GEMM v2: C[M,N] = A[M,K]*B[N,K]^T
// 128x128 tile, BK=64, XOR-swizzled LDS chunks (conflict-free frag reads).
// EPI=1: store fp32 C. EPI=2: fused rope/split epilogue (QKV producer).
#define CS_STRIDE 137
template <int EPI>
__global__ __launch_bounds__(256)
void gemm_bt2(const bf16* __restrict__ A, const bf16* __restrict__ B,
              float* __restrict__ Cf, int N, int Kc,
              const float* __restrict__ cosT, const float* __restrict__ sinT,
              bf16* __restrict__ Qo, bf16* __restrict__ Ko, bf16* __restrict__ Vo) {
  __shared__ bf16 smem[(EPI == 2) ? (128 * CS_STRIDE) : (128 * 128)];
  bf16* As = smem;
  bf16* Bs = smem + 128 * 64;

  const int tid  = threadIdx.x;
  const int lane = tid & 63;
  const int wave = tid >> 6;
  const int bm = blockIdx.x * 128;
  const int bn = blockIdx.y * 128;
  const int wm = (wave >> 1) * 64;
  const int wn = (wave & 1) * 64;
  const int r = lane & 15, q = lane >> 4;

  floatx4 acc[4][4];
  const floatx4 zero = {0.f, 0.f, 0.f, 0.f};
#pragma unroll
  for (int i = 0; i < 4; i++)
#pragma unroll
    for (int j = 0; j < 4; j++) acc[i][j] = zero;

  const int rl = lane >> 3, ch = lane & 7;
  const int srow = wave * 32 + rl;             // +i*8
  const int gch = ch ^ rl;
  const bf16* gA = A + (size_t)(bm + srow) * Kc + gch * 8;
  const bf16* gB = B + (size_t)(bn + srow) * Kc + gch * 8;

  for (int k0 = 0; k0 < Kc; k0 += 64) {
    __syncthreads();
#pragma unroll
    for (int i = 0; i < 4; i++)
      load_lds16(gA + k0 + (size_t)i * 8 * Kc, As + (wave * 32 + i * 8) * 64);
#pragma unroll
    for (int i = 0; i < 4; i++)
      load_lds16(gB + k0 + (size_t)i * 8 * Kc, Bs + (wave * 32 + i * 8) * 64);
    __syncthreads();

#pragma unroll
    for (int ks = 0; ks < 2; ks++) {
      short8 af[4], bfr[4];
#pragma unroll
      for (int mt = 0; mt < 4; mt++)
        af[mt] = *(const short8*)(As + (wm + mt * 16 + r) * 64 + ((ks * 4 + q) ^ (r & 7)) * 8);
#pragma unroll
      for (int nt = 0; nt < 4; nt++)
        bfr[nt] = *(const short8*)(Bs + (wn + nt * 16 + r) * 64 + ((ks * 4 + q) ^ (r & 7)) * 8);
#pragma unroll
      for (int mt = 0; mt < 4; mt++)
#pragma unroll
        for (int nt = 0; nt < 4; nt++)
          acc[mt][nt] = __builtin_amdgcn_mfma_f32_16x16x32_bf16(af[mt], bfr[nt], acc[mt][nt], 0, 0, 0);
    }
  }

  if (EPI == 1) {
#pragma unroll
    for (int mt = 0; mt < 4; mt++)
#pragma unroll
      for (int nt = 0; nt < 4; nt++)
#pragma unroll
        for (int reg = 0; reg < 4; reg++) {
          const int row = bm + wm + mt * 16 + q * 4 + reg;
          const int col = bn + wn + nt * 16 + r;
          Cf[(size_t)row * N + col] = acc[mt][nt][reg];
        }
  } else {
    // ---- fused rope/split epilogue: this block owns one head (hn = blockIdx.y)
    __syncthreads();   // all waves done reading As/Bs before aliasing with Cs
#pragma unroll
    for (int mt = 0; mt < 4; mt++)
#pragma unroll
      for (int nt = 0; nt < 4; nt++)
#pragma unroll
        for (int reg = 0; reg < 4; reg++)
          smem[(wm + mt * 16 + q * 4 + reg) * CS_STRIDE + wn + nt * 16 + r] =
              __float2bfloat16(acc[mt][nt][reg]);
    __syncthreads();

    const int hn = blockIdx.y;
    if (hn < N_Q + N_KV) {
      const float SCL = 0.12751744868673310f;  // 1/sqrt(128) * log2(e), Q only
      const bool isQ = (hn < N_Q);
      bf16* base = isQ ? (Qo + (size_t)bm * NH + hn * HDIM)
                       : (Ko + (size_t)bm * KH + (hn - N_Q) * HDIM);
      const int ostride = isQ ? NH : KH;
      for (int idx = tid; idx < 128 * 64; idx += 256) {
        const int row = idx >> 6, h = idx & 63;
        const float x1 = __bfloat162float(smem[row * CS_STRIDE + h]);
        const float x2 = __bfloat162float(smem[row * CS_STRIDE + h + 64]);
        const float cs = cosT[(bm + row) * 64 + h];
        const float sn = sinT[(bm + row) * 64 + h];
        float o1 = x1 * cs - x2 * sn;
        float o2 = x2 * cs + x1 * sn;
        if (isQ) { o1 *= SCL; o2 *= SCL; }
        bf16* d = base + (size_t)row * ostride;
        d[h]      = __float2bfloat16(o1);
        d[h + 64] = __float2bfloat16(o2);
      }
    } else {
      // V head: write V^T (KH x T)
      const int kh = hn - (N_Q + N_KV);
      for (int idx = tid; idx < 128 * 32; idx += 256) {
        const int h = idx >> 5, r4 = (idx & 31) * 4;
        union { bf16 h4[4]; unsigned long long u; } o;
#pragma unroll
        for (int j = 0; j < 4; j++) o.h4[j] = smem[(r4 + j) * CS_STRIDE + h];
        *(unsigned long long*)(Vo + ((size_t)kh * HDIM + h) * T_SEQ + bm + r4) = o.u;
      }
    }
  }
}

// ------------------------------------------------- causal GQA flash attention v3
// Fixed-shift softmax (shift-invariant => exact), deferred l-reduction,
// global_load_lds staging with source-chunk XOR swizzle.
// Block: 128 q rows (4 waves x 32), 64-col kv tiles; grid 512 = 2/CU paired big/small.
#define MSHIFT 8.0f
__global__ __launch_bounds__(256, 2)
void flash_attn(const bf16* __restrict__ Q, const bf16* __restrict__ Kk,
                const bf16* __restrict__ Vt, bf16* __restrict__ O) {
  const int id = blockIdx.x;
  const int n  = id & 31;
  const int kh = n >> 2;
  const int bt = (id < 256) ? (15 - (id >> 5)) : ((id - 256) >> 5);
  const int t0 = bt * 128;
  const int tid = threadIdx.x, lane = tid & 63, w = tid >> 6;
  const int r = lane & 15, q = lane >> 4;

  __shared__ bf16 Ks[64][128];     // [s][h], XOR-swizzled 16B chunks
  __shared__ bf16 Vs[128][64];     // [h][s], XOR-swizzled 16B chunks
  __shared__ bf16 Ps[4][32][72];   // per-wave P, padded

  // Q fragments (Q is pre-scaled by 1/sqrt(H)*log2e)
  short8 qf[2][4];
#pragma unroll
  for (int mf = 0; mf < 2; mf++) {
    const bf16* qrow = Q + (size_t)(t0 + w * 32 + mf * 16 + r) * NH + n * HDIM;
#pragma unroll
    for (int ks = 0; ks < 4; ks++)
      qf[mf][ks] = *(const short8*)(qrow + ks * 32 + q * 8);
  }

  floatx4 o_acc[2][8];
  const floatx4 zero = {0.f, 0.f, 0.f, 0.f};
#pragma unroll
  for (int mf = 0; mf < 2; mf++)
#pragma unroll
    for (int i = 0; i < 8; i++) o_acc[mf][i] = zero;
  float l_lane[2][4];
#pragma unroll
  for (int mf = 0; mf < 2; mf++)
#pragma unroll
    for (int i = 0; i < 4; i++) l_lane[mf][i] = 0.f;

  // staging lane roles (fixed): K rows of 256B = 16 chunks; V rows of 128B = 8 chunks
  const int krl = lane >> 4, kc = lane & 15;   // K: 4 rows/inst
  const int vrl = lane >> 3, vc = lane & 7;    // V: 8 rows/inst

  const int nIter = 2 * bt + 2;
  for (int it = 0; it < nIter; ++it) {
    const int s0 = it * 64;
    __syncthreads();   // everyone done reading previous tile
#pragma unroll
    for (int i = 0; i < 4; i++) {
      const int row = (w * 4 + i) * 4 + krl;           // 0..63
      load_lds16(Kk + (size_t)(s0 + row) * KH + kh * HDIM + (kc ^ (row & 7)) * 8,
                 &Ks[(w * 4 + i) * 4][0]);
    }
#pragma unroll
    for (int i = 0; i < 4; i++) {
      const int row = (w * 4 + i) * 8 + vrl;           // 0..127
      load_lds16(Vt + ((size_t)kh * HDIM + row) * T_SEQ + s0 + (vc ^ (row & 7)) * 8,
                 &Vs[(w * 4 + i) * 8][0]);
    }
    __syncthreads();   // vmcnt(0) drain + barrier: tile visible to all waves

    // S = Q K^T : per wave 32 q-rows x 64 kv-cols (in log2 units)
    floatx4 sa[2][4];
#pragma unroll
    for (int mf = 0; mf < 2; mf++)
#pragma unroll
      for (int nt = 0; nt < 4; nt++) sa[mf][nt] = zero;
#pragma unroll
    for (int ks = 0; ks < 4; ks++)
#pragma unroll
      for (int nt = 0; nt < 4; nt++) {
        const int krow = nt * 16 + r;
        const short8 kb = *(const short8*)(&Ks[krow][(((ks * 4 + q) ^ (krow & 7))) * 8]);
#pragma unroll
        for (int mf = 0; mf < 2; mf++)
          sa[mf][nt] = __builtin_amdgcn_mfma_f32_16x16x32_bf16(qf[mf][ks], kb, sa[mf][nt], 0, 0, 0);
      }

    // P = exp2(S - MSHIFT) with causal mask; accumulate per-lane partial l
#pragma unroll
    for (int mf = 0; mf < 2; mf++) {
      const int rbase = t0 + w * 32 + mf * 16;
      if (s0 + 63 > rbase) {
#pragma unroll
        for (int nt = 0; nt < 4; nt++)
#pragma unroll
          for (int reg = 0; reg < 4; reg++) {
            const int trow = rbase + q * 4 + reg;
            const int scol = s0 + nt * 16 + r;
            if (scol > trow) sa[mf][nt][reg] = -INFINITY;
          }
      }
#pragma unroll
      for (int nt = 0; nt < 4; nt++)
#pragma unroll
        for (int reg = 0; reg < 4; reg++) {
          const float p = exp2f(sa[mf][nt][reg] - MSHIFT);
          l_lane[mf][reg] += p;
          Ps[w][mf * 16 + q * 4 + reg][nt * 16 + r] = __float2bfloat16(p);
        }
    }

    // wave-private P: drain LDS writes before reads
    __asm__ volatile("s_waitcnt lgkmcnt(0)" ::: "memory");

    // O += P V
#pragma unroll
    for (int ks = 0; ks < 2; ks++) {
      short8 pa[2];
#pragma unroll
      for (int mf = 0; mf < 2; mf++)
        pa[mf] = *(const short8*)(&Ps[w][mf * 16 + r][ks * 32 + q * 8]);
#pragma unroll
      for (int ht = 0; ht < 8; ht++) {
        const int vrow = ht * 16 + r;
        const short8 vb = *(const short8*)(&Vs[vrow][(((ks * 4 + q) ^ (vrow & 7))) * 8]);
#pragma unroll
        for (int mf = 0; mf < 2; mf++)
          o_acc[mf][ht] = __builtin_amdgcn_mfma_f32_16x16x32_bf16(pa[mf], vb, o_acc[mf][ht], 0, 0, 0);
      }
    }
  }

  // epilogue: reduce l across the 16 col-lanes, divide, store
#pragma unroll
  for (int mf = 0; mf < 2; mf++)
#pragma unroll
    for (int reg = 0; reg < 4; reg++) {
      float v = l_lane[mf][reg];
      v += __shfl_xor(v, 1); v += __shfl_xor(v, 2);
      v += __shfl_xor(v, 4); v += __shfl_xor(v, 8);
      const float inv_l = 1.0f / v;
      const int trow = t0 + w * 32 + mf * 16 + q * 4 + reg;
#pragma unroll
      for (int ht = 0; ht < 8; ht++)
        O[(size_t)trow * NH + n * HDIM + ht * 16 + r] =
            __float2bfloat16(o_acc[mf][ht][reg] * inv_l);
    }
}

// ---------------------------------------------------------------- launch
extern "C" void kernel_launch(void* const* d_in, const int* in_sizes, int n_in,
                              void* d_out, int out_size, void* d_ws, size_t ws_size,
                              hipStream_t stream) {
  (void)in_sizes; (void)n_in; (void)out_size; (void)ws_size;
  const float* x   = (const float*)d_in[0];
  const int* pos   = (const int*)d_in[1];
  const float* w_q = (const float*)d_in[2];
  const float* w_k = (const float*)d_in[3];
  const float* w_v = (const float*)d_in[4];
  const float* w_o = (const float*)d_in[5];
  float* out = (float*)d_out;

  char* ws = (char*)d_ws;
  bf16*  xb   = (bf16*)(ws);                       // 2048x4096          @ 0
  bf16*  Bq   = (bf16*)(ws + (16ULL << 20));       // 6144x4096          @ 16M (reused for w_o^T)
  bf16*  Qr   = (bf16*)(ws + (64ULL << 20));       // 2048x4096          @ 64M
  bf16*  Kr   = (bf16*)(ws + (80ULL << 20));       // 2048x1024          @ 80M
  bf16*  Vt   = (bf16*)(ws + (84ULL << 20));       // (8*128) x 2048     @ 84M
  bf16*  Oatt = (bf16*)(ws + (88ULL << 20));       // 2048x4096          @ 88M
  float* ct   = (float*)(ws + (104ULL << 20));     // 2048x64 f32        @ 104M
  float* st   = (float*)(ws + (105ULL << 20));     // 2048x64 f32        @ 105M
  bf16*  woT  = Bq;

  cvt_bf16_kernel<<<(T_SEQ * D_MODEL / 4 + 255) / 256, 256, 0, stream>>>(x, xb, T_SEQ * D_MODEL / 4);
  sincos_tab<<<(T_SEQ * 64) / 256, 256, 0, stream>>>(pos, ct, st);
  transpose_cvt<<<dim3(NH / 64, D_MODEL / 64), 256, 0, stream>>>(w_q, Bq, D_MODEL, NH);
  transpose_cvt<<<dim3(KH / 64, D_MODEL / 64), 256, 0, stream>>>(w_k, Bq + (size_t)NH * D_MODEL, D_MODEL, KH);
  transpose_cvt<<<dim3(KH / 64, D_MODEL / 64), 256, 0, stream>>>(w_v, Bq + (size_t)(NH + KH) * D_MODEL, D_MODEL, KH);

  // fused QKV GEMM + rope/split epilogue
  gemm_bt2<2><<<dim3(T_SEQ / 128, QKV_W / 128), 256, 0, stream>>>(
      xb, Bq, nullptr, QKV_W, D_MODEL, ct, st, Qr, Kr, Vt);

  // w_o^T (reuses Bq region; stream-ordered after the QKV GEMM)
  transpose_cvt<<<dim3(D_MODEL / 64, NH / 64), 256, 0, stream>>>(w_o, woT, NH, D_MODEL);

  flash_attn<<<dim3(512), 256, 0, stream>>>(Qr, Kr, Vt, Oatt);

  gemm_bt2<1><<<dim3(T_SEQ / 128, D_MODEL / 128), 256, 0, stream>>>(
      Oatt, woT, out, D_MODEL, NH, nullptr, nullptr, nullptr, nullptr, nullptr);
}